// Round 4
// baseline (396.717 us; speedup 1.0000x reference)
//
#include <hip/hip_runtime.h>

// ---------------------------------------------------------------------------
// StructuralCoherenceLoss on MI355X
// Inputs:  d_in[0] structure        int32  [64,32,32,32]
//          d_in[1] block_embeddings f32    [64,32,32,32,32]  (B,C,X,Y,Z)
// Output:  d_out   f32 [5] = (total, l_conn, l_patch, l_smooth, l_support)
//
// Timing context (R1-R3 counters): two 1-GiB harness poison fills
// (~161 us each @ ~84% HBM peak) sit in the timed window => ~322 us fixed.
// Controllable slice ~65 us vs ~45 us compulsory floor. R3's 1-deep pipeline
// bought -8.8 us => smooth was latency-limited; this round doubles MLP depth.
//
// Grid = 1792 blocks (7/CU at 256 thr => single scheduling round):
//   blocks [0, PA)           : patch entropy (one wave per 4^3 patch)
//   blocks [PA, PA+ST)       : connectivity + support
//   blocks [PA+ST, PA+ST+SM) : smoothness, TWO (b,c) slices per block
//
// Smooth v4 (this round): 2-WIDE + 2-DEEP pipelined x-loop. Each iteration
// computes x and x+1 while the four loads for x+2/x+3 are in flight
// (2 KiB/wave HBM in flight steady-state, vs 1 KiB in v3). ~10 live float4
// => ~55-60 VGPR, inside the 64-VGPR cap of __launch_bounds__(256,7).
//   - dx from register (vp rotation)     -> no px load stream
//   - dz boundary via __shfl_down(v.x,1) -> no scalar peek stream
//   - dy load (+128B) overlaps block's own v lines -> L1/L2 hit
//
// Workspace (doubles):
//   [0,1024)      dx partials          (SM = 1024)
//   [1024,2048)   dy partials
//   [2048,3072)   dz partials
//   [3072,3584)   isolated partials    (ST = 512)
//   [3584,4096)   non-air partials
//   [4096,4608)   unsupported partials
//   [4608,4864)   entropy partials     (PA = 256)
// ---------------------------------------------------------------------------

#define SM_BLOCKS 1024
#define ST_BLOCKS 512
#define PA_BLOCKS 256
#define WS_DX  0
#define WS_DY  (SM_BLOCKS)
#define WS_DZ  (2 * SM_BLOCKS)
#define WS_ISO (3 * SM_BLOCKS)
#define WS_NA  (WS_ISO + ST_BLOCKS)
#define WS_UNS (WS_NA + ST_BLOCKS)
#define WS_ENT (WS_UNS + ST_BLOCKS)

__device__ __forceinline__ bool non_air(int t) {
    return !(t == 102 || t == 576 || t == 3352);
}

__device__ __forceinline__ double wave_red_d(double v) {
    #pragma unroll
    for (int off = 32; off > 0; off >>= 1) v += __shfl_down(v, off, 64);
    return v;
}
__device__ __forceinline__ float wave_red_f(float v) {
    #pragma unroll
    for (int off = 32; off > 0; off >>= 1) v += __shfl_down(v, off, 64);
    return v;
}
__device__ __forceinline__ int wave_red_i(int v) {
    #pragma unroll
    for (int off = 32; off > 0; off >>= 1) v += __shfl_down(v, off, 64);
    return v;
}

__device__ __forceinline__ float sad4(float4 a, float4 b) {
    return fabsf(a.x - b.x) + fabsf(a.y - b.y) + fabsf(a.z - b.z) + fabsf(a.w - b.w);
}

// --- smoothness body: 1024 blocks, TWO (b,c) slices each, 2-wide pipeline ---
__device__ void smooth_body(const float4* __restrict__ e4,
                            double* __restrict__ part, int bid) {
    const int tid = (int)threadIdx.x;           // 256 threads = all (z4, y)
    const int z4  = tid & 7;                    // which float4 along Z
    const int y   = tid >> 3;                   // 0..31
    const int oy  = (y < 31) ? 8 : 0;           // +1 in Y (float4 units); 0 => self => diff 0
    const float mzf = (z4 < 7) ? 1.0f : 0.0f;   // z chunk-boundary mask

    float ax = 0.0f, ay = 0.0f, az = 0.0f;

    #pragma unroll 1
    for (int sl = 0; sl < 2; ++sl) {
        const int base = (bid * 2 + sl) * 8192 + tid;   // slice = 8192 float4s

        // prologue: x=0 and x=1 load pairs in flight
        float4 vA = e4[base];
        float4 pA = e4[base + oy];
        float4 vB = e4[base + 256];
        float4 pB = e4[base + 256 + oy];
        float4 vp = vA;                          // x==0: sad4(vA,vp)==0 (no x-1 pair)

        #pragma unroll 1
        for (int x = 0; x < 30; x += 2) {
            // issue x+2 / x+3 loads FIRST: 4 loads (2 HBM, 2 cache-hit) fly
            // under the ~70 VALU ops of the two computations below.
            const int i2 = base + ((x + 2) << 8);       // x stride = 256 float4s
            const float4 vn0 = e4[i2];
            const float4 pn0 = e4[i2 + oy];
            const float4 vn1 = e4[i2 + 256];
            const float4 pn1 = e4[i2 + 256 + oy];

            float f = __shfl_down(vA.x, 1, 64);         // z4+1 boundary value
            az += fabsf(vA.y - vA.x) + fabsf(vA.z - vA.y) + fabsf(vA.w - vA.z)
                + mzf * fabsf(f - vA.w);
            ay += sad4(pA, vA);
            ax += sad4(vA, vp);

            f = __shfl_down(vB.x, 1, 64);
            az += fabsf(vB.y - vB.x) + fabsf(vB.z - vB.y) + fabsf(vB.w - vB.z)
                + mzf * fabsf(f - vB.w);
            ay += sad4(pB, vB);
            ax += sad4(vB, vA);

            vp = vB;
            vA = vn0; pA = pn0; vB = vn1; pB = pn1;
        }
        // epilogue: x = 30, 31
        {
            float f = __shfl_down(vA.x, 1, 64);
            az += fabsf(vA.y - vA.x) + fabsf(vA.z - vA.y) + fabsf(vA.w - vA.z)
                + mzf * fabsf(f - vA.w);
            ay += sad4(pA, vA);
            ax += sad4(vA, vp);

            f = __shfl_down(vB.x, 1, 64);
            az += fabsf(vB.y - vB.x) + fabsf(vB.z - vB.y) + fabsf(vB.w - vB.z)
                + mzf * fabsf(f - vB.w);
            ay += sad4(pB, vB);
            ax += sad4(vB, vA);
        }
    }

    double dxd = wave_red_d((double)ax);
    double dyd = wave_red_d((double)ay);
    double dzd = wave_red_d((double)az);
    __shared__ double sm[3][4];
    const int lane = threadIdx.x & 63, wid = threadIdx.x >> 6;
    if (lane == 0) { sm[0][wid] = dxd; sm[1][wid] = dyd; sm[2][wid] = dzd; }
    __syncthreads();
    if (threadIdx.x == 0) {
        part[WS_DX + bid] = sm[0][0] + sm[0][1] + sm[0][2] + sm[0][3];
        part[WS_DY + bid] = sm[1][0] + sm[1][1] + sm[1][2] + sm[1][3];
        part[WS_DZ + bid] = sm[2][0] + sm[2][1] + sm[2][2] + sm[2][3];
    }
}

// --- connectivity + support: 512 blocks, 16 iterations/thread ---------------
__device__ void struct_body(const int* __restrict__ s,
                            double* __restrict__ part, int bid) {
    const int t0 = bid * 256 + (int)threadIdx.x;   // < 2^17; bits 0..16 fixed
    const int z = t0 & 31, y = (t0 >> 5) & 31, x = (t0 >> 10) & 31;
    int iso = 0, nai = 0, unsup = 0;
    #pragma unroll 2
    for (int k = 0; k < 16; ++k) {
        const int idx = t0 + (k << 17);
        const int t = s[idx];
        if (non_air(t)) {
            ++nai;
            int ncnt = 0;
            bool below = false;
            if (x > 0)  ncnt += non_air(s[idx - 1024]);
            if (x < 31) ncnt += non_air(s[idx + 1024]);
            if (y > 0)  { below = non_air(s[idx - 32]); ncnt += below; }
            if (y < 31) ncnt += non_air(s[idx + 32]);
            if (z > 0)  ncnt += non_air(s[idx - 1]);
            if (z < 31) ncnt += non_air(s[idx + 1]);
            iso += (ncnt == 0);
            unsup += (y > 0 && !below);
        }
    }
    iso = wave_red_i(iso); nai = wave_red_i(nai); unsup = wave_red_i(unsup);
    __shared__ int sm[3][4];
    const int lane = threadIdx.x & 63, wid = threadIdx.x >> 6;
    if (lane == 0) { sm[0][wid] = iso; sm[1][wid] = nai; sm[2][wid] = unsup; }
    __syncthreads();
    if (threadIdx.x == 0) {
        part[WS_ISO + bid] = (double)(sm[0][0] + sm[0][1] + sm[0][2] + sm[0][3]);
        part[WS_NA  + bid] = (double)(sm[1][0] + sm[1][1] + sm[1][2] + sm[1][3]);
        part[WS_UNS + bid] = (double)(sm[2][0] + sm[2][1] + sm[2][2] + sm[2][3]);
    }
}

// --- patch entropy: one wave per 4x4x4 patch, 32 patches/wave ---------------
__device__ void patch_body(const int* __restrict__ s,
                           double* __restrict__ part, int bid) {
    const int lane = threadIdx.x & 63, wid = threadIdx.x >> 6;
    const int gwave = bid * 4 + wid;
    const int nwaves = PA_BLOCKS * 4;
    const int px = lane >> 4, py = (lane >> 2) & 3, pz = lane & 3;

    float esum = 0.0f;
    for (int pid = gwave; pid < 32768; pid += nwaves) {
        const int b = pid >> 9;
        const int rem = pid & 511;
        const int ix = rem >> 6, iy = (rem >> 3) & 7, iz = rem & 7;
        const int x = ix * 4 + px, y = iy * 4 + py, z = iz * 4 + pz;

        const int t = s[((b * 32 + x) * 32 + y) * 32 + z];
        const bool na = non_air(t);
        const int scount = __popcll(__ballot(na));

        int c = 0, minj = 64;
        #pragma unroll 8
        for (int j = 0; j < 64; ++j) {
            const int tj = __shfl(t, j, 64);
            if (tj == t) { ++c; if (j < minj) minj = j; }
        }
        if (na && minj == lane) {  // first occurrence of this token in the patch
            const float p = (float)c / (float)(scount > 1 ? scount : 1);
            esum += -p * logf(p + 1e-10f);
        }
    }
    const float w = wave_red_f(esum);
    __shared__ float smp[4];
    if (lane == 0) smp[wid] = w;
    __syncthreads();
    if (threadIdx.x == 0)
        part[WS_ENT + bid] = (double)(smp[0] + smp[1] + smp[2] + smp[3]);
}

// --- fused main kernel (patch/struct first => hide under smooth stream) -----
__global__ __launch_bounds__(256, 7) void fused_kernel(const int* __restrict__ s,
                                                       const float4* __restrict__ e4,
                                                       double* __restrict__ part) {
    const int bid = blockIdx.x;
    if (bid < PA_BLOCKS) {
        patch_body(s, part, bid);
    } else if (bid < PA_BLOCKS + ST_BLOCKS) {
        struct_body(s, part, bid - PA_BLOCKS);
    } else {
        smooth_body(e4, part, bid - PA_BLOCKS - ST_BLOCKS);
    }
}

// --- combine -----------------------------------------------------------------
__global__ __launch_bounds__(256) void finalize_kernel(const double* __restrict__ part,
                                                       float* __restrict__ out) {
    __shared__ double sm[4];
    __shared__ double res[7];
    const int lane = threadIdx.x & 63, wid = threadIdx.x >> 6;
    const int base[7] = {WS_DX, WS_DY, WS_DZ, WS_ISO, WS_NA, WS_UNS, WS_ENT};
    const int len[7]  = {SM_BLOCKS, SM_BLOCKS, SM_BLOCKS, ST_BLOCKS, ST_BLOCKS, ST_BLOCKS, PA_BLOCKS};
    for (int k = 0; k < 7; ++k) {
        double a = 0.0;
        for (int i = threadIdx.x; i < len[k]; i += 256) a += part[base[k] + i];
        a = wave_red_d(a);
        if (lane == 0) sm[wid] = a;
        __syncthreads();
        if (threadIdx.x == 0) res[k] = sm[0] + sm[1] + sm[2] + sm[3];
        __syncthreads();
    }
    if (threadIdx.x == 0) {
        const double na = res[4];
        const double l_conn    = res[3] / (na + 1e-6);
        const double l_support = res[5] / (na + 1e-6);
        const double l_patch   = res[6] / (32768.0 + 1e-6);
        const double nd = 65011712.0;  // 64*32*31*32*32 (same for dx, dy, dz)
        const double l_smooth  = (res[0] / nd + res[1] / nd + res[2] / nd) / 3.0;
        const double total = 0.5 * l_conn + 0.3 * l_patch + 0.1 * l_smooth + 0.2 * l_support;
        out[0] = (float)total;
        out[1] = (float)l_conn;
        out[2] = (float)l_patch;
        out[3] = (float)l_smooth;
        out[4] = (float)l_support;
    }
}

extern "C" void kernel_launch(void* const* d_in, const int* in_sizes, int n_in,
                              void* d_out, int out_size, void* d_ws, size_t ws_size,
                              hipStream_t stream) {
    const int*   s   = (const int*)d_in[0];
    const float* emb = (const float*)d_in[1];
    float* out   = (float*)d_out;
    double* part = (double*)d_ws;

    fused_kernel<<<PA_BLOCKS + ST_BLOCKS + SM_BLOCKS, 256, 0, stream>>>(
        s, (const float4*)emb, part);
    finalize_kernel<<<1, 256, 0, stream>>>(part, out);
}

// Round 5
// 386.820 us; speedup vs baseline: 1.0256x; 1.0256x over previous
//
#include <hip/hip_runtime.h>

// ---------------------------------------------------------------------------
// StructuralCoherenceLoss on MI355X
// Inputs:  d_in[0] structure        int32  [64,32,32,32]
//          d_in[1] block_embeddings f32    [64,32,32,32,32]  (B,C,X,Y,Z)
// Output:  d_out   f32 [5] = (total, l_conn, l_patch, l_smooth, l_support)
//
// Timing context (R1-R4 counters): two 1-GiB harness poison fills
// (~160 us each @ ~84% HBM peak) sit in the timed window => ~321 us fixed.
// Controllable slice ~66 us vs ~50 us compulsory floor.
// R4's 2-wide pipeline REGRESSED (+9.7 us: VGPR pressure vs 64-cap =>
// spill/serialized loads). This is the exact R3 kernel (best measured,
// 387.0 us): 1-deep software pipeline, ~40 VGPR, 7 blocks/CU.
//
// Grid = 1792 blocks (7/CU at 256 thr => single scheduling round):
//   blocks [0, PA)           : patch entropy (one wave per 4^3 patch)
//   blocks [PA, PA+ST)       : connectivity + support
//   blocks [PA+ST, PA+ST+SM) : smoothness, TWO (b,c) slices per block
//
// Smooth: thread owns (z4,y), iterates over X, loads rotated 1 ahead.
//   - dx from register (vprev)           -> no px load stream
//   - dz boundary via __shfl_down(v.x,1) -> no scalar peek stream
//   - dy load (+128B) overlaps block's own v lines -> L1 hit
//
// Workspace (doubles):
//   [0,1024)      dx partials          (SM = 1024)
//   [1024,2048)   dy partials
//   [2048,3072)   dz partials
//   [3072,3584)   isolated partials    (ST = 512)
//   [3584,4096)   non-air partials
//   [4096,4608)   unsupported partials
//   [4608,4864)   entropy partials     (PA = 256)
// ---------------------------------------------------------------------------

#define SM_BLOCKS 1024
#define ST_BLOCKS 512
#define PA_BLOCKS 256
#define WS_DX  0
#define WS_DY  (SM_BLOCKS)
#define WS_DZ  (2 * SM_BLOCKS)
#define WS_ISO (3 * SM_BLOCKS)
#define WS_NA  (WS_ISO + ST_BLOCKS)
#define WS_UNS (WS_NA + ST_BLOCKS)
#define WS_ENT (WS_UNS + ST_BLOCKS)

__device__ __forceinline__ bool non_air(int t) {
    return !(t == 102 || t == 576 || t == 3352);
}

__device__ __forceinline__ double wave_red_d(double v) {
    #pragma unroll
    for (int off = 32; off > 0; off >>= 1) v += __shfl_down(v, off, 64);
    return v;
}
__device__ __forceinline__ float wave_red_f(float v) {
    #pragma unroll
    for (int off = 32; off > 0; off >>= 1) v += __shfl_down(v, off, 64);
    return v;
}
__device__ __forceinline__ int wave_red_i(int v) {
    #pragma unroll
    for (int off = 32; off > 0; off >>= 1) v += __shfl_down(v, off, 64);
    return v;
}

__device__ __forceinline__ float sad4(float4 a, float4 b) {
    return fabsf(a.x - b.x) + fabsf(a.y - b.y) + fabsf(a.z - b.z) + fabsf(a.w - b.w);
}

// --- smoothness body: 1024 blocks, TWO (b,c) slices each, pipelined x-loop --
__device__ void smooth_body(const float4* __restrict__ e4,
                            double* __restrict__ part, int bid) {
    const int tid = (int)threadIdx.x;           // 256 threads = all (z4, y)
    const int z4  = tid & 7;                    // which float4 along Z
    const int y   = tid >> 3;                   // 0..31
    const int oy  = (y < 31) ? 8 : 0;           // +1 in Y (float4 units); 0 => self => diff 0
    const float mzf = (z4 < 7) ? 1.0f : 0.0f;   // z chunk-boundary mask

    float ax = 0.0f, ay = 0.0f, az = 0.0f;

    #pragma unroll 1
    for (int sl = 0; sl < 2; ++sl) {
        const int base = (bid * 2 + sl) * 8192 + tid;   // slice = 8192 float4s

        // prologue: x = 0 loads in flight
        float4 v = e4[base];
        float4 p = e4[base + oy];
        float4 vp = v;                           // x==0: sad4(v,vp)==0 (no x-1 pair)

        #pragma unroll 1
        for (int x = 0; x < 31; ++x) {
            // issue next iteration's loads FIRST; they fly under this
            // iteration's ~55 VALU ops instead of stalling the wave.
            const int inext = base + ((x + 1) << 8);    // x stride = 256 float4s
            const float4 vn = e4[inext];
            const float4 pn = e4[inext + oy];

            const float f = __shfl_down(v.x, 1, 64);    // z4+1 boundary value
            az += fabsf(v.y - v.x) + fabsf(v.z - v.y) + fabsf(v.w - v.z)
                + mzf * fabsf(f - v.w);
            ay += sad4(p, v);
            ax += sad4(v, vp);
            vp = v; v = vn; p = pn;
        }
        // epilogue: x = 31
        {
            const float f = __shfl_down(v.x, 1, 64);
            az += fabsf(v.y - v.x) + fabsf(v.z - v.y) + fabsf(v.w - v.z)
                + mzf * fabsf(f - v.w);
            ay += sad4(p, v);
            ax += sad4(v, vp);
        }
    }

    double dxd = wave_red_d((double)ax);
    double dyd = wave_red_d((double)ay);
    double dzd = wave_red_d((double)az);
    __shared__ double sm[3][4];
    const int lane = threadIdx.x & 63, wid = threadIdx.x >> 6;
    if (lane == 0) { sm[0][wid] = dxd; sm[1][wid] = dyd; sm[2][wid] = dzd; }
    __syncthreads();
    if (threadIdx.x == 0) {
        part[WS_DX + bid] = sm[0][0] + sm[0][1] + sm[0][2] + sm[0][3];
        part[WS_DY + bid] = sm[1][0] + sm[1][1] + sm[1][2] + sm[1][3];
        part[WS_DZ + bid] = sm[2][0] + sm[2][1] + sm[2][2] + sm[2][3];
    }
}

// --- connectivity + support: 512 blocks, 16 iterations/thread ---------------
__device__ void struct_body(const int* __restrict__ s,
                            double* __restrict__ part, int bid) {
    const int t0 = bid * 256 + (int)threadIdx.x;   // < 2^17; bits 0..16 fixed
    const int z = t0 & 31, y = (t0 >> 5) & 31, x = (t0 >> 10) & 31;
    int iso = 0, nai = 0, unsup = 0;
    #pragma unroll 2
    for (int k = 0; k < 16; ++k) {
        const int idx = t0 + (k << 17);
        const int t = s[idx];
        if (non_air(t)) {
            ++nai;
            int ncnt = 0;
            bool below = false;
            if (x > 0)  ncnt += non_air(s[idx - 1024]);
            if (x < 31) ncnt += non_air(s[idx + 1024]);
            if (y > 0)  { below = non_air(s[idx - 32]); ncnt += below; }
            if (y < 31) ncnt += non_air(s[idx + 32]);
            if (z > 0)  ncnt += non_air(s[idx - 1]);
            if (z < 31) ncnt += non_air(s[idx + 1]);
            iso += (ncnt == 0);
            unsup += (y > 0 && !below);
        }
    }
    iso = wave_red_i(iso); nai = wave_red_i(nai); unsup = wave_red_i(unsup);
    __shared__ int sm[3][4];
    const int lane = threadIdx.x & 63, wid = threadIdx.x >> 6;
    if (lane == 0) { sm[0][wid] = iso; sm[1][wid] = nai; sm[2][wid] = unsup; }
    __syncthreads();
    if (threadIdx.x == 0) {
        part[WS_ISO + bid] = (double)(sm[0][0] + sm[0][1] + sm[0][2] + sm[0][3]);
        part[WS_NA  + bid] = (double)(sm[1][0] + sm[1][1] + sm[1][2] + sm[1][3]);
        part[WS_UNS + bid] = (double)(sm[2][0] + sm[2][1] + sm[2][2] + sm[2][3]);
    }
}

// --- patch entropy: one wave per 4x4x4 patch, 32 patches/wave ---------------
__device__ void patch_body(const int* __restrict__ s,
                           double* __restrict__ part, int bid) {
    const int lane = threadIdx.x & 63, wid = threadIdx.x >> 6;
    const int gwave = bid * 4 + wid;
    const int nwaves = PA_BLOCKS * 4;
    const int px = lane >> 4, py = (lane >> 2) & 3, pz = lane & 3;

    float esum = 0.0f;
    for (int pid = gwave; pid < 32768; pid += nwaves) {
        const int b = pid >> 9;
        const int rem = pid & 511;
        const int ix = rem >> 6, iy = (rem >> 3) & 7, iz = rem & 7;
        const int x = ix * 4 + px, y = iy * 4 + py, z = iz * 4 + pz;

        const int t = s[((b * 32 + x) * 32 + y) * 32 + z];
        const bool na = non_air(t);
        const int scount = __popcll(__ballot(na));

        int c = 0, minj = 64;
        #pragma unroll 8
        for (int j = 0; j < 64; ++j) {
            const int tj = __shfl(t, j, 64);
            if (tj == t) { ++c; if (j < minj) minj = j; }
        }
        if (na && minj == lane) {  // first occurrence of this token in the patch
            const float p = (float)c / (float)(scount > 1 ? scount : 1);
            esum += -p * logf(p + 1e-10f);
        }
    }
    const float w = wave_red_f(esum);
    __shared__ float smp[4];
    if (lane == 0) smp[wid] = w;
    __syncthreads();
    if (threadIdx.x == 0)
        part[WS_ENT + bid] = (double)(smp[0] + smp[1] + smp[2] + smp[3]);
}

// --- fused main kernel (patch/struct first => hide under smooth stream) -----
__global__ __launch_bounds__(256, 7) void fused_kernel(const int* __restrict__ s,
                                                       const float4* __restrict__ e4,
                                                       double* __restrict__ part) {
    const int bid = blockIdx.x;
    if (bid < PA_BLOCKS) {
        patch_body(s, part, bid);
    } else if (bid < PA_BLOCKS + ST_BLOCKS) {
        struct_body(s, part, bid - PA_BLOCKS);
    } else {
        smooth_body(e4, part, bid - PA_BLOCKS - ST_BLOCKS);
    }
}

// --- combine -----------------------------------------------------------------
__global__ __launch_bounds__(256) void finalize_kernel(const double* __restrict__ part,
                                                       float* __restrict__ out) {
    __shared__ double sm[4];
    __shared__ double res[7];
    const int lane = threadIdx.x & 63, wid = threadIdx.x >> 6;
    const int base[7] = {WS_DX, WS_DY, WS_DZ, WS_ISO, WS_NA, WS_UNS, WS_ENT};
    const int len[7]  = {SM_BLOCKS, SM_BLOCKS, SM_BLOCKS, ST_BLOCKS, ST_BLOCKS, ST_BLOCKS, PA_BLOCKS};
    for (int k = 0; k < 7; ++k) {
        double a = 0.0;
        for (int i = threadIdx.x; i < len[k]; i += 256) a += part[base[k] + i];
        a = wave_red_d(a);
        if (lane == 0) sm[wid] = a;
        __syncthreads();
        if (threadIdx.x == 0) res[k] = sm[0] + sm[1] + sm[2] + sm[3];
        __syncthreads();
    }
    if (threadIdx.x == 0) {
        const double na = res[4];
        const double l_conn    = res[3] / (na + 1e-6);
        const double l_support = res[5] / (na + 1e-6);
        const double l_patch   = res[6] / (32768.0 + 1e-6);
        const double nd = 65011712.0;  // 64*32*31*32*32 (same for dx, dy, dz)
        const double l_smooth  = (res[0] / nd + res[1] / nd + res[2] / nd) / 3.0;
        const double total = 0.5 * l_conn + 0.3 * l_patch + 0.1 * l_smooth + 0.2 * l_support;
        out[0] = (float)total;
        out[1] = (float)l_conn;
        out[2] = (float)l_patch;
        out[3] = (float)l_smooth;
        out[4] = (float)l_support;
    }
}

extern "C" void kernel_launch(void* const* d_in, const int* in_sizes, int n_in,
                              void* d_out, int out_size, void* d_ws, size_t ws_size,
                              hipStream_t stream) {
    const int*   s   = (const int*)d_in[0];
    const float* emb = (const float*)d_in[1];
    float* out   = (float*)d_out;
    double* part = (double*)d_ws;

    fused_kernel<<<PA_BLOCKS + ST_BLOCKS + SM_BLOCKS, 256, 0, stream>>>(
        s, (const float4*)emb, part);
    finalize_kernel<<<1, 256, 0, stream>>>(part, out);
}